// Round 3
// baseline (1172.891 us; speedup 1.0000x reference)
//
#include <hip/hip_runtime.h>
#include <math.h>

// SmartMoEFFN: top-2 MoE with folded router.
// B=4 S=2048 D=1024 H=4096 E=8 TOPK=2. Tokens T=8192, pairs=16384.
// GEMMs: 8-phase 256x256/BK=64 schedule. Buffer-liveness-correct staging:
//   buf1 free p1-p4 (stage v=2it+1 early at p1-p2, vmcnt(0) at end p4),
//   buf0 free p5-p8 (stage 2it+2 at p5-p6, vmcnt(0) at end p8).
// T2 LDS swizzle (16B-slot ^= row&7, both-sides) + T5 setprio around MFMA.

typedef unsigned short u16;
typedef __attribute__((ext_vector_type(8))) short short8_t;
typedef __attribute__((ext_vector_type(4))) float f32x4;

#define TOKENS 8192
#define DDIM 1024
#define HDIM 4096
#define NEXP 8
#define ECAP 8192           // max tokens per expert
#define MAX_SLOTS 71        // sum ceil(n_e/256) <= 16384/256 + 7
#define NBINS 64            // aux-loss accumulation bins

struct __align__(8) us4 { u16 x, y, z, w; };

__device__ __forceinline__ u16 f2bf(float f) {
  unsigned int u = __float_as_uint(f);
  u += 0x7fffu + ((u >> 16) & 1u);   // RTNE
  return (u16)(u >> 16);
}

__device__ __forceinline__ void gload_lds16(const void* g, void* l) {
  __builtin_amdgcn_global_load_lds((const __attribute__((address_space(1))) void*)g,
                                   (__attribute__((address_space(3))) void*)l, 16, 0, 0);
}

// ---------------- fp32 -> bf16 flat convert (x) ----------------
__global__ void cvt_bf16_kernel(const float* __restrict__ src, u16* __restrict__ dst, long n) {
  long i = ((long)blockIdx.x * 256 + threadIdx.x) * 4;
  if (i < n) {
    float4 v = *(const float4*)&src[i];
    us4 o; o.x = f2bf(v.x); o.y = f2bf(v.y); o.z = f2bf(v.z); o.w = f2bf(v.w);
    *(us4*)&dst[i] = o;
  }
}

// ---------------- fp32 [R][C] -> bf16 [C][R] per expert (blockIdx.z) ----------------
__global__ void transpose_cvt_kernel(const float* __restrict__ src, u16* __restrict__ dst,
                                     int R, int C) {
  __shared__ float tile[32][33];
  size_t mat = (size_t)R * C;
  const float* s = src + (size_t)blockIdx.z * mat;
  u16* d = dst + (size_t)blockIdx.z * mat;
  int r0 = blockIdx.y * 32, c0 = blockIdx.x * 32;
  int tr = threadIdx.x >> 3, tc = (threadIdx.x & 7) * 4;
  float4 v = *(const float4*)&s[(size_t)(r0 + tr) * C + (c0 + tc)];
  tile[tr][tc + 0] = v.x; tile[tr][tc + 1] = v.y;
  tile[tr][tc + 2] = v.z; tile[tr][tc + 3] = v.w;
  __syncthreads();
  int oc = tr, orr = tc;
  us4 o;
  o.x = f2bf(tile[orr + 0][oc]); o.y = f2bf(tile[orr + 1][oc]);
  o.z = f2bf(tile[orr + 2][oc]); o.w = f2bf(tile[orr + 3][oc]);
  *(us4*)&d[(size_t)(c0 + oc) * R + (r0 + orr)] = o;
}

// ---------------- crW[d][e] = sum_k ctx_W[d][k] * r_W[k][e] ----------------
__global__ void crw_kernel(const float* __restrict__ ctxW, const float* __restrict__ rW,
                           float* __restrict__ crW) {
  __shared__ float lbuf[32];
  int d = blockIdx.x, tid = threadIdx.x;
  float acc[8] = {0,0,0,0,0,0,0,0};
  for (int k = tid; k < DDIM; k += 256) {
    float c = ctxW[(size_t)d * DDIM + k];
    float4 r0 = *(const float4*)&rW[k * 8];
    float4 r1 = *(const float4*)&rW[k * 8 + 4];
    acc[0] += c * r0.x; acc[1] += c * r0.y; acc[2] += c * r0.z; acc[3] += c * r0.w;
    acc[4] += c * r1.x; acc[5] += c * r1.y; acc[6] += c * r1.z; acc[7] += c * r1.w;
  }
  int w = tid >> 6, lane = tid & 63;
  #pragma unroll
  for (int off = 32; off; off >>= 1) {
    #pragma unroll
    for (int e = 0; e < 8; e++) acc[e] += __shfl_down(acc[e], off);
  }
  if (lane == 0) {
    #pragma unroll
    for (int e = 0; e < 8; e++) lbuf[w * 8 + e] = acc[e];
  }
  __syncthreads();
  if (tid == 0) {
    #pragma unroll
    for (int e = 0; e < 8; e++)
      crW[d * 8 + e] = lbuf[e] + lbuf[8 + e] + lbuf[16 + e] + lbuf[24 + e];
  }
}

// ---------------- cbase[b][e] = (ctx_b + quality[b]*qW + q_b) . rW[:,e] + r_b[e] ----------------
__global__ void cbase_kernel(const float* __restrict__ ctx_b, const float* __restrict__ qW,
                             const float* __restrict__ q_b, const float* __restrict__ quality,
                             const float* __restrict__ rW, const float* __restrict__ r_b,
                             float* __restrict__ cbase) {
  __shared__ float lbuf[32];
  int b = blockIdx.x, tid = threadIdx.x;
  float qv = quality[b];
  float acc[8] = {0,0,0,0,0,0,0,0};
  for (int d = tid; d < DDIM; d += 256) {
    float base = ctx_b[d] + qv * qW[d] + q_b[d];
    float4 r0 = *(const float4*)&rW[d * 8];
    float4 r1 = *(const float4*)&rW[d * 8 + 4];
    acc[0] += base * r0.x; acc[1] += base * r0.y; acc[2] += base * r0.z; acc[3] += base * r0.w;
    acc[4] += base * r1.x; acc[5] += base * r1.y; acc[6] += base * r1.z; acc[7] += base * r1.w;
  }
  int w = tid >> 6, lane = tid & 63;
  #pragma unroll
  for (int off = 32; off; off >>= 1) {
    #pragma unroll
    for (int e = 0; e < 8; e++) acc[e] += __shfl_down(acc[e], off);
  }
  if (lane == 0) {
    #pragma unroll
    for (int e = 0; e < 8; e++) lbuf[w * 8 + e] = acc[e];
  }
  __syncthreads();
  if (tid == 0) {
    #pragma unroll
    for (int e = 0; e < 8; e++)
      cbase[b * 8 + e] = lbuf[e] + lbuf[8 + e] + lbuf[16 + e] + lbuf[24 + e] + r_b[e];
  }
}

// ---------------- router: LN stats + 16 dots + top2 + aux partials + bucketing ----------------
__global__ void router_kernel(const float* __restrict__ x, const float* __restrict__ ctx,
    const float* __restrict__ rn_g, const float* __restrict__ rn_b,
    const float* __restrict__ cn_g, const float* __restrict__ cn_b,
    const float* __restrict__ rW, const float* __restrict__ crW,
    const float* __restrict__ cbase, const float* __restrict__ temp_p,
    int* __restrict__ token_list, float* __restrict__ gate_list,
    int* __restrict__ counts, float* __restrict__ aux) {
  __shared__ float rbuf[16];
  __shared__ float lbuf[32];
  const int t = blockIdx.x;
  const int tid = threadIdx.x;
  const int b = t >> 11;
  const float* xr = x + (size_t)t * DDIM;
  const float* cr = ctx + (size_t)t * DDIM;
  float xv[4], cv[4];
  #pragma unroll
  for (int k = 0; k < 4; k++) { int d = tid + k * 256; xv[k] = xr[d]; cv[k] = cr[d]; }
  float sx = 0, sxx = 0, sc = 0, scc = 0;
  #pragma unroll
  for (int k = 0; k < 4; k++) {
    sx += xv[k]; sxx += xv[k] * xv[k];
    sc += cv[k]; scc += cv[k] * cv[k];
  }
  #pragma unroll
  for (int off = 32; off; off >>= 1) {
    sx += __shfl_down(sx, off); sxx += __shfl_down(sxx, off);
    sc += __shfl_down(sc, off); scc += __shfl_down(scc, off);
  }
  int w = tid >> 6, lane = tid & 63;
  if (lane == 0) {
    rbuf[w * 4 + 0] = sx; rbuf[w * 4 + 1] = sxx;
    rbuf[w * 4 + 2] = sc; rbuf[w * 4 + 3] = scc;
  }
  __syncthreads();
  sx  = rbuf[0] + rbuf[4] + rbuf[8]  + rbuf[12];
  sxx = rbuf[1] + rbuf[5] + rbuf[9]  + rbuf[13];
  sc  = rbuf[2] + rbuf[6] + rbuf[10] + rbuf[14];
  scc = rbuf[3] + rbuf[7] + rbuf[11] + rbuf[15];
  const float invD = 1.f / 1024.f;
  float mx = sx * invD, vx = sxx * invD - mx * mx;
  float mc = sc * invD, vc = scc * invD - mc * mc;
  float rsx = rsqrtf(vx + 1e-5f), rsc = rsqrtf(vc + 1e-5f);
  float acc[8] = {0,0,0,0,0,0,0,0};
  #pragma unroll
  for (int k = 0; k < 4; k++) {
    int d = tid + k * 256;
    float lx = (xv[k] - mx) * rsx * rn_g[d] + rn_b[d];
    float lc = (cv[k] - mc) * rsc * cn_g[d] + cn_b[d];
    float4 r0 = *(const float4*)&rW[d * 8];
    float4 r1 = *(const float4*)&rW[d * 8 + 4];
    float4 c0 = *(const float4*)&crW[d * 8];
    float4 c1 = *(const float4*)&crW[d * 8 + 4];
    acc[0] += lx * r0.x + lc * c0.x; acc[1] += lx * r0.y + lc * c0.y;
    acc[2] += lx * r0.z + lc * c0.z; acc[3] += lx * r0.w + lc * c0.w;
    acc[4] += lx * r1.x + lc * c1.x; acc[5] += lx * r1.y + lc * c1.y;
    acc[6] += lx * r1.z + lc * c1.z; acc[7] += lx * r1.w + lc * c1.w;
  }
  #pragma unroll
  for (int off = 32; off; off >>= 1) {
    #pragma unroll
    for (int e = 0; e < 8; e++) acc[e] += __shfl_down(acc[e], off);
  }
  if (lane == 0) {
    #pragma unroll
    for (int e = 0; e < 8; e++) lbuf[w * 8 + e] = acc[e];
  }
  __syncthreads();
  if (tid == 0) {
    float inv_t = 1.f / fmaxf(temp_p[0], 0.25f);
    float lg[8];
    #pragma unroll
    for (int e = 0; e < 8; e++)
      lg[e] = (lbuf[e] + lbuf[8 + e] + lbuf[16 + e] + lbuf[24 + e] + cbase[b * 8 + e]) * inv_t;
    int i0 = 0;
    #pragma unroll
    for (int e = 1; e < 8; e++) if (lg[e] > lg[i0]) i0 = e;
    int i1 = -1;
    #pragma unroll
    for (int e = 0; e < 8; e++) if (e != i0 && (i1 < 0 || lg[e] > lg[i1])) i1 = e;
    float e1v = __expf(lg[i1] - lg[i0]);
    float g0 = 1.f / (1.f + e1v), g1 = e1v / (1.f + e1v);
    float m8 = lg[i0];
    float pe[8], se = 0.f;
    #pragma unroll
    for (int e = 0; e < 8; e++) { pe[e] = expf(lg[e] - m8); se += pe[e]; }
    float inv_se = 1.f / se;
    float z = m8 + logf(se);
    float entc = 0.f;
    #pragma unroll
    for (int e = 0; e < 8; e++) {
      float p = pe[e] * inv_se;
      entc -= p * logf(fmaxf(p, 1e-9f));
    }
    int bin = (t & (NBINS - 1)) * 12;
    #pragma unroll
    for (int e = 0; e < 8; e++) atomicAdd(&aux[bin + e], pe[e] * inv_se);
    atomicAdd(&aux[bin + 8], z * z);
    atomicAdd(&aux[bin + 9], entc);
    int p0 = atomicAdd(&counts[i0], 1);
    token_list[i0 * ECAP + p0] = t; gate_list[i0 * ECAP + p0] = g0;
    int p1 = atomicAdd(&counts[i1], 1);
    token_list[i1 * ECAP + p1] = t; gate_list[i1 * ECAP + p1] = g1;
  }
}

// ---------------- finalize: 256-row tile table, list padding, aux scalars ----------------
__global__ void finalize_kernel(const int* __restrict__ counts, const float* __restrict__ aux,
                                int* __restrict__ token_list, float* __restrict__ gate_list,
                                int4* __restrict__ table, float* __restrict__ out_scalars) {
  __shared__ int scnt[NEXP], stl[NEXP], sbase[NEXP];
  __shared__ float sred[16];
  const int tid = threadIdx.x;
  if (tid < NEXP) {
    int c = counts[tid];
    scnt[tid] = c;
    stl[tid] = (c + 255) >> 8;
  }
  __syncthreads();
  if (tid == 0) {
    int s = 0;
    for (int e = 0; e < NEXP; e++) { sbase[e] = s; s += stl[e]; }
  }
  __syncthreads();
  for (int slot = tid; slot < MAX_SLOTS; slot += 256) {
    int4 v = make_int4(-1, 0, 0, 0);
    #pragma unroll
    for (int e = 0; e < NEXP; e++) {
      int rel = slot - sbase[e];
      if (rel >= 0 && rel < stl[e]) {
        int rv = scnt[e] - rel * 256;
        if (rv > 256) rv = 256;
        v = make_int4(e, rel * 256, rv, 0);
      }
    }
    table[slot] = v;
  }
  // list padding: at most 255 pad entries per expert
  for (int idx = tid; idx < NEXP * 256; idx += 256) {
    int e = idx >> 8, p = idx & 255;
    int pos = scnt[e] + p;
    if (pos < stl[e] * 256) {
      token_list[e * ECAP + pos] = 0;
      gate_list[e * ECAP + pos] = 0.f;
    }
  }
  if (tid < 10) {
    float s = 0.f;
    #pragma unroll 8
    for (int bn = 0; bn < NBINS; bn++) s += aux[bn * 12 + tid];
    sred[tid] = s;
  }
  __syncthreads();
  if (tid == 0) {
    float lb = 0.f;
    #pragma unroll
    for (int e = 0; e < NEXP; e++) {
      float im = sred[e] * (1.f / 8192.f);
      float dd = im - 0.125f;
      lb += dd * dd;
    }
    lb *= (1.f / 8.f);
    float rz = sred[8] * (1.f / 8192.f);
    float ent = sred[9] * (1.f / 8192.f);
    out_scalars[0] = lb;
    out_scalars[1] = rz;
    out_scalars[2] = ent;
    out_scalars[3] = lb + 0.001f * rz - 0.001f * ent;
  }
}

// ================= 8-phase 256x256 MFMA GEMM =================
// 512 threads = 8 waves (2M x 4N), per-wave C = 128x64 = acc[8][4] frags.
// LDS: 2 dbuf x {A:256x64, B:256x64} bf16 = 128 KiB, 1 block/CU.
// Swizzle: 16B-slot index ^= (row&7) on gload_lds SOURCE and on ds_read addr.
// Buffer liveness: buf0 consumed p1-p4 (even tiles), buf1 consumed p5-p8 (odd).
//   -> stage odd tile v=2it+1 into buf1 at p1-p2 (free: old contents consumed
//      in prev iter p5-p8), drain vmcnt(0) at end p4 (~3 phases after issue).
//   -> stage even tile 2it+2 into buf0 at p5-p6 (buf0 free after p4),
//      drain vmcnt(0) at end p8.
// MODE 0: h = gelu(gather(xbf) @ W1t[e]^T + b1[e]), K=1024, N=4096
// MODE 1: out[tok] += gate * (h @ W2t[e]^T + b2[e]), K=4096 (split 2x2048), N=1024

#define BAR   asm volatile("s_barrier" ::: "memory")
#define LGKM0 asm volatile("s_waitcnt lgkmcnt(0)" ::: "memory")
#define VMC8  asm volatile("s_waitcnt vmcnt(8)" ::: "memory")
#define VMC0  asm volatile("s_waitcnt vmcnt(0)" ::: "memory")

template <int MODE>
__launch_bounds__(512, 2)
__global__ void moe_gemm8_kernel(const u16* __restrict__ Asrc, const u16* __restrict__ Bt,
    const float* __restrict__ bias, const int* __restrict__ token_list,
    const float* __restrict__ gate_list, const int4* __restrict__ table,
    u16* __restrict__ h_out, float* __restrict__ out) {
  constexpr int KSTRIDE = (MODE == 0) ? DDIM : HDIM;   // row stride of A and B
  constexpr int ND      = (MODE == 0) ? HDIM : DDIM;
  constexpr int NT      = (MODE == 0) ? (DDIM / 64) : (2048 / 64);  // K-tiles per block
  constexpr int ITERS   = NT / 2;

  const int slot = blockIdx.y;
  const int4 tb = table[slot];
  const int e = tb.x;
  if (e < 0) return;
  const int row0 = tb.y, rv = tb.z;
  const int n0 = blockIdx.x * 256;
  const int kz = (MODE == 1) ? blockIdx.z : 0;
  const int kbase = kz * 2048;

  const int tid = threadIdx.x;
  const int lane = tid & 63, w = tid >> 6;
  const int lr = lane & 15, quad = lane >> 4;

  __shared__ __align__(16) u16 lds[65536];   // 128 KiB: [buf][A|B][256*64]

  // ---- staging pointers (per-lane global src, pre-inverse-swizzled) ----
  const u16* bbase = Bt + (size_t)e * ((size_t)ND * KSTRIDE);
  const u16* pA[2][2];
  const u16* pB[2][2];
  #pragma unroll
  for (int j = 0; j < 2; ++j) {
    int c = j * 512 + tid;
    int r = c >> 3;
    int kc = (c & 7) ^ (r & 7);            // inverse swizzle on source
    #pragma unroll
    for (int h = 0; h < 2; ++h) {
      if constexpr (MODE == 0) {
        int tok = token_list[e * ECAP + row0 + h * 128 + r];
        pA[h][j] = Asrc + (size_t)tok * KSTRIDE + kc * 8;
      } else {
        pA[h][j] = Asrc + ((size_t)slot * 256 + h * 128 + r) * (size_t)KSTRIDE + kbase + kc * 8;
      }
      pB[h][j] = bbase + (size_t)(n0 + h * 128 + r) * KSTRIDE + kbase + kc * 8;
    }
  }

#define STAGE_A(h, tt) do { int _bo = ((tt)&1)*32768 + (h)*8192; \
    gload_lds16(pA[h][0] + (tt)*64, &lds[_bo + tid*8]); \
    gload_lds16(pA[h][1] + (tt)*64, &lds[_bo + 4096 + tid*8]); } while (0)
#define STAGE_B(h, tt) do { int _bo = ((tt)&1)*32768 + 16384 + (h)*8192; \
    gload_lds16(pB[h][0] + (tt)*64, &lds[_bo + tid*8]); \
    gload_lds16(pB[h][1] + (tt)*64, &lds[_bo + 4096 + tid*8]); } while (0)

  // ---- ds_read lane constants (swizzled) ----
  const int aRow = ((w >> 2) * 128 + lr) * 64;          // u16 index
  const int bRow = 16384 + ((w & 3) * 64 + lr) * 64;
  const int kx0 = ((0 + quad) ^ (lr & 7)) * 8;
  const int kx1 = ((4 + quad) ^ (lr & 7)) * 8;

  f32x4 acc[8][4];
  #pragma unroll
  for (int i = 0; i < 8; i++)
    #pragma unroll
    for (int j = 0; j < 4; j++) acc[i][j] = (f32x4){0.f, 0.f, 0.f, 0.f};

  short8_t a[4][2], b[2][2];

#define LDA(MQ, BUF) do { const u16* _p = &lds[(BUF)*32768 + aRow + (MQ)*4096]; \
    a[0][0] = *(const short8_t*)(_p + kx0);        a[0][1] = *(const short8_t*)(_p + kx1); \
    a[1][0] = *(const short8_t*)(_p + 1024 + kx0); a[1][1] = *(const short8_t*)(_p + 1024 + kx1); \
    a[2][0] = *(const short8_t*)(_p + 2048 + kx0); a[2][1] = *(const short8_t*)(_p + 2048 + kx1); \
    a[3][0] = *(const short8_t*)(_p + 3072 + kx0); a[3][1] = *(const short8_t*)(_p + 3072 + kx1); \
  } while (0)
#define LDB(NQ, BUF) do { const u16* _p = &lds[(BUF)*32768 + bRow + (NQ)*2048]; \
    b[0][0] = *(const short8_t*)(_p + kx0);        b[0][1] = *(const short8_t*)(_p + kx1); \
    b[1][0] = *(const short8_t*)(_p + 1024 + kx0); b[1][1] = *(const short8_t*)(_p + 1024 + kx1); \
  } while (0)
#define MMA(MQ, NQ) do { \
    __builtin_amdgcn_s_setprio(1); \
    _Pragma("unroll") \
    for (int kk2 = 0; kk2 < 2; ++kk2) \
      _Pragma("unroll") \
      for (int i2 = 0; i2 < 4; ++i2) \
        _Pragma("unroll") \
        for (int j2 = 0; j2 < 2; ++j2) \
          acc[(MQ)*4 + i2][(NQ)*2 + j2] = __builtin_amdgcn_mfma_f32_16x16x32_bf16( \
              a[i2][kk2], b[j2][kk2], acc[(MQ)*4 + i2][(NQ)*2 + j2], 0, 0, 0); \
    __builtin_amdgcn_s_setprio(0); \
  } while (0)

  // ---- prologue: t0 -> buf0 (8 loads), t1 -> buf1 (8 loads) ----
  STAGE_A(0, 0); STAGE_A(1, 0); STAGE_B(0, 0); STAGE_B(1, 0);
  STAGE_A(0, 1); STAGE_A(1, 1); STAGE_B(0, 1); STAGE_B(1, 1);
  VMC8;   // t0 complete; t1's 8 loads in flight
  BAR;

  for (int it = 0; it < ITERS; ++it) {
    const int v = 2 * it + 1, u2 = 2 * it + 2;
    const bool sv = (it > 0), su = (u2 < NT);
    // ---- p1: t_even (buf0) quadrant (0,0); stage v.A -> buf1 ----
    LDA(0, 0); LDB(0, 0);
    if (sv) { STAGE_A(0, v); STAGE_A(1, v); }
    BAR; LGKM0; MMA(0, 0); BAR;
    // ---- p2: (0,1); stage v.B -> buf1 ----
    LDB(1, 0);
    if (sv) { STAGE_B(0, v); STAGE_B(1, v); }
    BAR; LGKM0; MMA(0, 1); BAR;
    // ---- p3: (1,1) ----
    LDA(1, 0);
    BAR; LGKM0; MMA(1, 1); BAR;
    // ---- p4: (1,0); drain v (issued ~3 phases ago) ----
    LDB(0, 0);
    VMC0;
    BAR; LGKM0; MMA(1, 0); BAR;
    // ---- p5: t_odd (buf1) quadrant (0,0); stage u2.A -> buf0 ----
    LDA(0, 1); LDB(0, 1);
    if (su) { STAGE_A(0, u2); STAGE_A(1, u2); }
    BAR; LGKM0; MMA(0, 0); BAR;
    // ---- p6: (0,1); stage u2.B -> buf0 ----
    LDB(1, 1);
    if (su) { STAGE_B(0, u2); STAGE_B(1, u2); }
    BAR; LGKM0; MMA(0, 1); BAR;
    // ---- p7: (1,1) ----
    LDA(1, 1);
    BAR; LGKM0; MMA(1, 1); BAR;
    // ---- p8: (1,0); drain u2 ----
    LDB(0, 1);
    VMC0;
    BAR; LGKM0; MMA(1, 0); BAR;
  }

#undef STAGE_A
#undef STAGE_B
#undef LDA
#undef LDB
#undef MMA

  // ---- epilogue ----
  float bcol[4];
  #pragma unroll
  for (int j = 0; j < 4; j++) {
    int col = n0 + (w & 3) * 64 + j * 16 + lr;
    bcol[j] = (MODE == 1 && kz != 0) ? 0.f : bias[e * ND + col];
  }

  if constexpr (MODE == 0) {
    #pragma unroll
    for (int i = 0; i < 8; i++) {
      #pragma unroll
      for (int r = 0; r < 4; r++) {
        int row = (w >> 2) * 128 + i * 16 + quad * 4 + r;
        size_t ro = ((size_t)slot * 256 + row) * (size_t)HDIM;
        #pragma unroll
        for (int j = 0; j < 4; j++) {
          int col = n0 + (w & 3) * 64 + j * 16 + lr;
          float v = acc[i][j][r] + bcol[j];
          v = 0.5f * v * (1.f + erff(v * 0.70710678118654752f));
          h_out[ro + col] = f2bf(v);
        }
      }
    }
  } else {
    #pragma unroll
    for (int i = 0; i < 8; i++) {
      #pragma unroll
      for (int r = 0; r < 4; r++) {
        int row = (w >> 2) * 128 + i * 16 + quad * 4 + r;
        if (row < rv) {
          int tok = token_list[e * ECAP + row0 + row];
          float g = gate_list[e * ECAP + row0 + row];
          float* orow = out + (size_t)tok * DDIM;
          #pragma unroll
          for (int j = 0; j < 4; j++) {
            int col = n0 + (w & 3) * 64 + j * 16 + lr;
            atomicAdd(&orow[col], g * (acc[i][j][r] + bcol[j]));
          }
        }
      }
    }
  }
}

extern "C" void kernel_launch(void* const* d_in, const int* in_sizes, int n_in,
                              void* d_out, int out_size, void* d_ws, size_t ws_size,
                              hipStream_t stream) {
  const float* x      = (const float*)d_in[0];
  const float* ctx    = (const float*)d_in[1];
  const float* qual   = (const float*)d_in[2];
  const float* rn_g   = (const float*)d_in[3];
  const float* rn_b   = (const float*)d_in[4];
  const float* cn_g   = (const float*)d_in[5];
  const float* cn_b   = (const float*)d_in[6];
  const float* ctx_W  = (const float*)d_in[7];
  const float* ctx_b  = (const float*)d_in[8];
  const float* q_W    = (const float*)d_in[9];
  const float* q_b    = (const float*)d_in[10];
  const float* r_W    = (const float*)d_in[11];
  const float* r_b    = (const float*)d_in[12];
  const float* temp   = (const float*)d_in[13];
  const float* W1     = (const float*)d_in[14];
  const float* b1     = (const float*)d_in[15];
  const float* W2     = (const float*)d_in[16];
  const float* b2     = (const float*)d_in[17];
  float* out = (float*)d_out;

  char* ws = (char*)d_ws;
  size_t o = 0;
  auto alloc = [&](size_t bytes) { void* p = ws + o; o += (bytes + 255) & ~(size_t)255; return p; };
  u16*   xbf        = (u16*)alloc((size_t)TOKENS * DDIM * 2);
  u16*   W1t        = (u16*)alloc((size_t)NEXP * HDIM * DDIM * 2);
  u16*   W2t        = (u16*)alloc((size_t)NEXP * DDIM * HDIM * 2);
  u16*   hbuf       = (u16*)alloc((size_t)MAX_SLOTS * 256 * HDIM * 2);
  float* crW        = (float*)alloc(DDIM * 8 * 4);
  float* cb         = (float*)alloc(32 * 4);
  int*   token_list = (int*)alloc(NEXP * ECAP * 4);
  float* gate_list  = (float*)alloc(NEXP * ECAP * 4);
  int*   counts     = (int*)alloc((8 + NBINS * 12) * 4);  // counts[8] then aux bins
  float* aux        = (float*)(counts + 8);
  int4*  table      = (int4*)alloc(MAX_SLOTS * 16);
  (void)ws_size; (void)n_in; (void)in_sizes;

  (void)hipMemsetAsync(d_out, 0, (size_t)out_size * 4, stream);
  (void)hipMemsetAsync(counts, 0, (8 + NBINS * 12) * 4, stream);

  cvt_bf16_kernel<<<(TOKENS * DDIM) / 1024, 256, 0, stream>>>(x, xbf, (long)TOKENS * DDIM);
  transpose_cvt_kernel<<<dim3(HDIM / 32, DDIM / 32, NEXP), 256, 0, stream>>>(W1, W1t, DDIM, HDIM);
  transpose_cvt_kernel<<<dim3(DDIM / 32, HDIM / 32, NEXP), 256, 0, stream>>>(W2, W2t, HDIM, DDIM);
  crw_kernel<<<DDIM, 256, 0, stream>>>(ctx_W, r_W, crW);
  cbase_kernel<<<4, 256, 0, stream>>>(ctx_b, q_W, q_b, qual, r_W, r_b, cb);
  router_kernel<<<TOKENS, 256, 0, stream>>>(x, ctx, rn_g, rn_b, cn_g, cn_b, r_W, crW, cb, temp,
                                            token_list, gate_list, counts, aux);
  finalize_kernel<<<1, 256, 0, stream>>>(counts, aux, token_list, gate_list, table,
                                         out + (size_t)TOKENS * DDIM);
  moe_gemm8_kernel<0><<<dim3(HDIM / 256, MAX_SLOTS), 512, 0, stream>>>(
      xbf, W1t, b1, token_list, gate_list, table, hbuf, nullptr);
  moe_gemm8_kernel<1><<<dim3(DDIM / 256, MAX_SLOTS, 2), 512, 0, stream>>>(
      hbuf, W2t, b2, token_list, gate_list, table, nullptr, out);
}